// Round 1
// baseline (439.609 us; speedup 1.0000x reference)
//
#include <hip/hip_runtime.h>

#define FFT_N   4096
#define LOG2N   12
#define THREADS 512
#define NPAD    4224   // 4096 + 4096/32 padding

__device__ __forceinline__ int padidx(int i) { return i + (i >> 5); }

__global__ __launch_bounds__(THREADS) void fft4096_kernel(
    const float* __restrict__ x_re, const float* __restrict__ x_im,
    const float* __restrict__ W_re, const float* __restrict__ W_im,
    const int* __restrict__ bitrev,
    float* __restrict__ out, int batch)
{
    __shared__ float sre[NPAD];
    __shared__ float sim[NPAD];
    const int row = blockIdx.x;
    const int tid = threadIdx.x;
    const float* xr = x_re + (size_t)row * FFT_N;
    const float* xi = x_im + (size_t)row * FFT_N;

    // Coalesced float4 load, bit-reverse scatter into padded LDS.
    // bitrev is an involution: y[bitrev[i]] = x[i]  <=>  y[i] = x[bitrev[i]].
    for (int i4 = tid; i4 < FFT_N / 4; i4 += THREADS) {
        const float4 vr = ((const float4*)xr)[i4];
        const float4 vi = ((const float4*)xi)[i4];
        const int4  br = ((const int4*)bitrev)[i4];
        sre[padidx(br.x)] = vr.x; sim[padidx(br.x)] = vi.x;
        sre[padidx(br.y)] = vr.y; sim[padidx(br.y)] = vi.y;
        sre[padidx(br.z)] = vr.z; sim[padidx(br.z)] = vi.z;
        sre[padidx(br.w)] = vr.w; sim[padidx(br.w)] = vi.w;
    }
    __syncthreads();

    // 12 in-place radix-2 DIT stages.
    for (int stage = 0; stage < LOG2N; ++stage) {
        const int stride = 1 << stage;
#pragma unroll
        for (int bb = 0; bb < (FFT_N / 2) / THREADS; ++bb) {
            const int b  = tid + bb * THREADS;
            const int j  = b & (stride - 1);
            const int i0 = ((b >> stage) << (stage + 1)) + j;
            const int i1 = i0 + stride;
            const int twi = j << (LOG2N - 1 - stage);
            const float wr = W_re[twi];
            const float wi = W_im[twi];
            const int p0 = padidx(i0), p1 = padidx(i1);
            const float ur = sre[p0], ui = sim[p0];
            const float lr = sre[p1], li = sim[p1];
            const float tr = wr * lr - wi * li;
            const float ti = wr * li + wi * lr;
            sre[p0] = ur + tr; sim[p0] = ui + ti;
            sre[p1] = ur - tr; sim[p1] = ui - ti;
        }
        __syncthreads();
    }

    // Coalesced float4 store in natural order.
    float* yr = out + (size_t)row * FFT_N;
    float* yi = out + (size_t)batch * FFT_N + (size_t)row * FFT_N;
    for (int i4 = tid; i4 < FFT_N / 4; i4 += THREADS) {
        const int i = i4 * 4;
        float4 vr, vi;
        vr.x = sre[padidx(i + 0)]; vr.y = sre[padidx(i + 1)];
        vr.z = sre[padidx(i + 2)]; vr.w = sre[padidx(i + 3)];
        vi.x = sim[padidx(i + 0)]; vi.y = sim[padidx(i + 1)];
        vi.z = sim[padidx(i + 2)]; vi.w = sim[padidx(i + 3)];
        ((float4*)yr)[i4] = vr;
        ((float4*)yi)[i4] = vi;
    }
}

extern "C" void kernel_launch(void* const* d_in, const int* in_sizes, int n_in,
                              void* d_out, int out_size, void* d_ws, size_t ws_size,
                              hipStream_t stream) {
    const float* x_re   = (const float*)d_in[0];
    const float* x_im   = (const float*)d_in[1];
    const float* W_re   = (const float*)d_in[2];
    const float* W_im   = (const float*)d_in[3];
    const int*   bitrev = (const int*)d_in[4];
    const int batch = in_sizes[0] / FFT_N;
    float* out = (float*)d_out;
    fft4096_kernel<<<batch, THREADS, 0, stream>>>(x_re, x_im, W_re, W_im, bitrev, out, batch);
}

// Round 2
// 153.855 us; speedup vs baseline: 2.8573x; 2.8573x over previous
//
#include <hip/hip_runtime.h>

#define FFT_N   4096
#define THREADS 512

// Complex as float2: x = re, y = im.
__device__ __forceinline__ float2 cmul(float2 w, float2 v) {
    return make_float2(fmaf(w.x, v.x, -w.y * v.y), fmaf(w.x, v.y, w.y * v.x));
}
__device__ __forceinline__ float2 cmni(float2 v) {   // v * (-i)
    return make_float2(v.y, -v.x);
}
__device__ __forceinline__ void bfly(float2& a, float2& b, float2 w) {
    float2 t = cmul(w, b);
    b = make_float2(a.x - t.x, a.y - t.y);
    a = make_float2(a.x + t.x, a.y + t.y);
}

// XOR-fold swizzle: bank-pair bits = i[0..3] ^ i[4..7] ^ i[8..11].
// Verified conflict-free for every access pattern used below.
__device__ __forceinline__ int swz(int i) {
    return i ^ ((i >> 4) & 15) ^ ((i >> 8) & 15);
}

// One radix-8 block = 3 radix-2 stages (strides s, 2s, 4s) on u[0..7],
// where u[j] holds the element at index base + j*s.
// A = W[r<<(11-3p)], B = W[r<<(10-3p)], C = W[r<<(9-3p)], D = W[(r<<(9-3p))+512].
__device__ __forceinline__ void radix8(float2 u[8], float2 A, float2 B, float2 C, float2 D) {
    // stage 3p: pairs (2m, 2m+1), twiddle A
    bfly(u[0], u[1], A); bfly(u[2], u[3], A); bfly(u[4], u[5], A); bfly(u[6], u[7], A);
    // stage 3p+1: pairs (j, j+2), j in {0,1,4,5}; twiddle B, then B*(-i) for odd j
    float2 Bn = cmni(B);
    bfly(u[0], u[2], B); bfly(u[1], u[3], Bn); bfly(u[4], u[6], B); bfly(u[5], u[7], Bn);
    // stage 3p+2: pairs (j, j+4), j=0..3; twiddles C, D, C*(-i), D*(-i)
    float2 Cn = cmni(C), Dn = cmni(D);
    bfly(u[0], u[4], C); bfly(u[1], u[5], D); bfly(u[2], u[6], Cn); bfly(u[3], u[7], Dn);
}

__global__ __launch_bounds__(THREADS) void fft4096_r8_kernel(
    const float* __restrict__ x_re, const float* __restrict__ x_im,
    const float* __restrict__ W_re, const float* __restrict__ W_im,
    float* __restrict__ out, int batch)
{
    __shared__ float2 lds[FFT_N];
    const int t   = threadIdx.x;
    const int row = blockIdx.x;
    const float* xr = x_re + (size_t)row * FFT_N;
    const float* xi = x_im + (size_t)row * FFT_N;

    // ---- pass 0 (stages 0..2): load bit-reversed group straight from global.
    // u[j] = y[8*rev9(t) + j] = x[bitrev12(8*rev9(t)+j)] = x[t + 512*rev3(j)].
    // Fully coalesced (lane-consecutive dwords per j).
    float2 u[8];
    u[0] = make_float2(xr[t],        xi[t]);
    u[1] = make_float2(xr[t + 2048], xi[t + 2048]);
    u[2] = make_float2(xr[t + 1024], xi[t + 1024]);
    u[3] = make_float2(xr[t + 3072], xi[t + 3072]);
    u[4] = make_float2(xr[t + 512],  xi[t + 512]);
    u[5] = make_float2(xr[t + 2560], xi[t + 2560]);
    u[6] = make_float2(xr[t + 1536], xi[t + 1536]);
    u[7] = make_float2(xr[t + 3584], xi[t + 3584]);

    const float c = 0.70710678118654752f;
    radix8(u, make_float2(1.f, 0.f), make_float2(1.f, 0.f),
              make_float2(1.f, 0.f), make_float2(c, -c));

    // write y[8*rev9(t) + j]
    const int g0 = (int)(__brev((unsigned)t) >> 23);   // rev9(t)
#pragma unroll
    for (int j = 0; j < 8; ++j) lds[swz(8 * g0 + j)] = u[j];
    __syncthreads();

    // ---- pass 1 (stages 3..5): groups {b1 + 8j}, r1 = b1 mod 8 = t&7.
    // b1 places t3 at bit 7 / t4 at bit 6 so the LDS pattern is conflict-free.
    const int b1 = (t & 7) | (((t >> 4) & 1) << 6) | (((t >> 3) & 1) << 7) | ((t >> 5) << 8);
    const int r1 = t & 7;
    float2 A = make_float2(W_re[r1 << 8], W_im[r1 << 8]);
    float2 B = make_float2(W_re[r1 << 7], W_im[r1 << 7]);
    float2 C = make_float2(W_re[r1 << 6], W_im[r1 << 6]);
    float2 D = make_float2(W_re[(r1 << 6) + 512], W_im[(r1 << 6) + 512]);
#pragma unroll
    for (int j = 0; j < 8; ++j) u[j] = lds[swz(b1 + 8 * j)];
    radix8(u, A, B, C, D);
#pragma unroll
    for (int j = 0; j < 8; ++j) lds[swz(b1 + 8 * j)] = u[j];   // same slots: no pre-barrier
    __syncthreads();

    // ---- pass 2 (stages 6..8): groups {b2 + 64j}, r2 = t&63.
    const int b2 = (t & 63) | ((t >> 6) << 9);
    const int r2 = t & 63;
    A = make_float2(W_re[r2 << 5], W_im[r2 << 5]);
    B = make_float2(W_re[r2 << 4], W_im[r2 << 4]);
    C = make_float2(W_re[r2 << 3], W_im[r2 << 3]);
    D = make_float2(W_re[(r2 << 3) + 512], W_im[(r2 << 3) + 512]);
#pragma unroll
    for (int j = 0; j < 8; ++j) u[j] = lds[swz(b2 + 64 * j)];
    radix8(u, A, B, C, D);
#pragma unroll
    for (int j = 0; j < 8; ++j) lds[swz(b2 + 64 * j)] = u[j];
    __syncthreads();

    // ---- pass 3 (stages 9..11): groups {t + 512j}, r3 = t.
    A = make_float2(W_re[t << 2], W_im[t << 2]);
    B = make_float2(W_re[t << 1], W_im[t << 1]);
    C = make_float2(W_re[t],      W_im[t]);
    D = make_float2(W_re[t + 512], W_im[t + 512]);
#pragma unroll
    for (int j = 0; j < 8; ++j) u[j] = lds[swz(t + 512 * j)];
    radix8(u, A, B, C, D);

    // direct coalesced store: thread t holds y[t + 512j]
    float*       yr = out + (size_t)row * FFT_N;
    float*       yi = out + (size_t)batch * FFT_N + (size_t)row * FFT_N;
#pragma unroll
    for (int j = 0; j < 8; ++j) {
        yr[t + 512 * j] = u[j].x;
        yi[t + 512 * j] = u[j].y;
    }
}

extern "C" void kernel_launch(void* const* d_in, const int* in_sizes, int n_in,
                              void* d_out, int out_size, void* d_ws, size_t ws_size,
                              hipStream_t stream) {
    const float* x_re = (const float*)d_in[0];
    const float* x_im = (const float*)d_in[1];
    const float* W_re = (const float*)d_in[2];
    const float* W_im = (const float*)d_in[3];
    // d_in[4] = bitrev table (unused: bit-reversal is computed in-kernel)
    const int batch = in_sizes[0] / FFT_N;
    float* out = (float*)d_out;
    fft4096_r8_kernel<<<batch, THREADS, 0, stream>>>(x_re, x_im, W_re, W_im, out, batch);
}

// Round 3
// 112.803 us; speedup vs baseline: 3.8971x; 1.3639x over previous
//
#include <hip/hip_runtime.h>

#define FFT_N   4096
#define THREADS 512

__device__ __forceinline__ float2 cmul(float2 w, float2 v) {
    return make_float2(fmaf(w.x, v.x, -w.y * v.y), fmaf(w.x, v.y, w.y * v.x));
}
__device__ __forceinline__ float2 cmni(float2 v) { return make_float2(v.y, -v.x); }
__device__ __forceinline__ void bfly(float2& a, float2& b, float2 w) {
    float2 t = cmul(w, b);
    b = make_float2(a.x - t.x, a.y - t.y);
    a = make_float2(a.x + t.x, a.y + t.y);
}
// XOR-fold swizzle: bank-pair bits = i[0..3] ^ i[4..7] ^ i[8..11]; conflict-free
// for all access patterns below (verified round 2: conflicts 1.7e7 -> 1e6).
__device__ __forceinline__ int swz(int i) { return i ^ ((i >> 4) & 15) ^ ((i >> 8) & 15); }

// lgkmcnt(0)-only barrier: does NOT drain vmcnt, so prefetched global loads
// stay in flight across compute phases (raw s_barrier, HK pattern).
__device__ __forceinline__ void bar() {
    asm volatile("s_waitcnt lgkmcnt(0)" ::: "memory");
    __builtin_amdgcn_s_barrier();
}

// radix-8 = 3 radix-2 stages on u[j] = element (base + j*s).
__device__ __forceinline__ void radix8(float2 u[8], float2 A, float2 B, float2 C, float2 D) {
    bfly(u[0], u[1], A); bfly(u[2], u[3], A); bfly(u[4], u[5], A); bfly(u[6], u[7], A);
    float2 Bn = cmni(B);
    bfly(u[0], u[2], B); bfly(u[1], u[3], Bn); bfly(u[4], u[6], B); bfly(u[5], u[7], Bn);
    float2 Cn = cmni(C), Dn = cmni(D);
    bfly(u[0], u[4], C); bfly(u[1], u[5], D); bfly(u[2], u[6], Cn); bfly(u[3], u[7], Dn);
}

// Coalesced bit-reversed load: u[j] = x[t + 512*rev3(j)].
__device__ __forceinline__ void load_row(float2 u[8], const float* __restrict__ xr,
                                         const float* __restrict__ xi, int t) {
    u[0] = make_float2(xr[t],        xi[t]);
    u[1] = make_float2(xr[t + 2048], xi[t + 2048]);
    u[2] = make_float2(xr[t + 1024], xi[t + 1024]);
    u[3] = make_float2(xr[t + 3072], xi[t + 3072]);
    u[4] = make_float2(xr[t + 512],  xi[t + 512]);
    u[5] = make_float2(xr[t + 2560], xi[t + 2560]);
    u[6] = make_float2(xr[t + 1536], xi[t + 1536]);
    u[7] = make_float2(xr[t + 3584], xi[t + 3584]);
}

// 4 radix-8 passes; twiddles derived from row-invariant C1/C2/C3 (B=C^2, A=B^2, D=C*W512).
__device__ __forceinline__ void process_row(float2 u[8], float2* lds, int t,
        float2 C1, float2 C2, float2 C3, float2 w512,
        float* __restrict__ yr, float* __restrict__ yi)
{
    const float2 one = make_float2(1.f, 0.f);
    // pass 0 (stages 0..2): twiddles are 1,1,1,W[512]
    radix8(u, one, one, one, w512);
    const int g0 = (int)(__brev((unsigned)t) >> 23);   // rev9(t)
#pragma unroll
    for (int j = 0; j < 8; ++j) lds[swz(8 * g0 + j)] = u[j];
    bar();

    // pass 1 (stages 3..5)
    const int b1 = (t & 7) | (((t >> 4) & 1) << 6) | (((t >> 3) & 1) << 7) | ((t >> 5) << 8);
#pragma unroll
    for (int j = 0; j < 8; ++j) u[j] = lds[swz(b1 + 8 * j)];
    {
        float2 B = cmul(C1, C1), A = cmul(B, B), D = cmul(C1, w512);
        radix8(u, A, B, C1, D);
    }
#pragma unroll
    for (int j = 0; j < 8; ++j) lds[swz(b1 + 8 * j)] = u[j];   // same slots: no pre-barrier
    bar();

    // pass 2 (stages 6..8)
    const int b2 = (t & 63) | ((t >> 6) << 9);
#pragma unroll
    for (int j = 0; j < 8; ++j) u[j] = lds[swz(b2 + 64 * j)];
    {
        float2 B = cmul(C2, C2), A = cmul(B, B), D = cmul(C2, w512);
        radix8(u, A, B, C2, D);
    }
#pragma unroll
    for (int j = 0; j < 8; ++j) lds[swz(b2 + 64 * j)] = u[j];
    bar();

    // pass 3 (stages 9..11): thread t ends holding y[t + 512j] -> direct coalesced store
#pragma unroll
    for (int j = 0; j < 8; ++j) u[j] = lds[swz(t + 512 * j)];
    {
        float2 B = cmul(C3, C3), A = cmul(B, B), D = cmul(C3, w512);
        radix8(u, A, B, C3, D);
    }
#pragma unroll
    for (int j = 0; j < 8; ++j) { yr[t + 512 * j] = u[j].x; yi[t + 512 * j] = u[j].y; }
    bar();   // pass-3 reads must finish before next row's pass-0 scatter reuses LDS
}

__global__ __launch_bounds__(THREADS) void fft4096_pipe_kernel(
    const float* __restrict__ x_re, const float* __restrict__ x_im,
    const float* __restrict__ W_re, const float* __restrict__ W_im,
    float* __restrict__ out, int batch, int rows_per)
{
    __shared__ float2 lds[FFT_N];
    const int t = threadIdx.x;

    // Row-invariant twiddle bases (1 gather per table per pass, hoisted out of row loop).
    const float2 C1 = make_float2(W_re[(t & 7) << 6],  W_im[(t & 7) << 6]);
    const float2 C2 = make_float2(W_re[(t & 63) << 3], W_im[(t & 63) << 3]);
    const float2 C3 = make_float2(W_re[t],             W_im[t]);
    const float2 w512 = make_float2(0.70710678118654752f, -0.70710678118654752f);

    const int row0 = blockIdx.x * rows_per;
    float2 ua[8], ub[8];

    if (rows_per & 1) {   // fallback (not hit for batch=8192): no pipelining
        for (int i = 0; i < rows_per; ++i) {
            const int r = row0 + i;
            load_row(ua, x_re + (size_t)r * FFT_N, x_im + (size_t)r * FFT_N, t);
            process_row(ua, lds, t, C1, C2, C3, w512,
                        out + (size_t)r * FFT_N, out + ((size_t)batch + r) * FFT_N);
        }
        return;
    }

    // Software pipeline: prefetch row i+1's 16 loads before computing row i.
    load_row(ua, x_re + (size_t)row0 * FFT_N, x_im + (size_t)row0 * FFT_N, t);
    for (int i = 0; i < rows_per; i += 2) {
        const int ra = row0 + i, rb = ra + 1;
        load_row(ub, x_re + (size_t)rb * FFT_N, x_im + (size_t)rb * FFT_N, t);
        process_row(ua, lds, t, C1, C2, C3, w512,
                    out + (size_t)ra * FFT_N, out + ((size_t)batch + ra) * FFT_N);
        if (i + 2 < rows_per) {
            const int rc = ra + 2;
            load_row(ua, x_re + (size_t)rc * FFT_N, x_im + (size_t)rc * FFT_N, t);
        }
        process_row(ub, lds, t, C1, C2, C3, w512,
                    out + (size_t)rb * FFT_N, out + ((size_t)batch + rb) * FFT_N);
    }
}

extern "C" void kernel_launch(void* const* d_in, const int* in_sizes, int n_in,
                              void* d_out, int out_size, void* d_ws, size_t ws_size,
                              hipStream_t stream) {
    const float* x_re = (const float*)d_in[0];
    const float* x_im = (const float*)d_in[1];
    const float* W_re = (const float*)d_in[2];
    const float* W_im = (const float*)d_in[3];
    // d_in[4] = bitrev (unused: bit-reversal folded into the pass-0 load pattern)
    const int batch = in_sizes[0] / FFT_N;
    float* out = (float*)d_out;

    int rows_per = 8;
    while (rows_per > 1 && (batch % rows_per)) rows_per >>= 1;
    const int grid = batch / rows_per;
    fft4096_pipe_kernel<<<grid, THREADS, 0, stream>>>(x_re, x_im, W_re, W_im, out, batch, rows_per);
}